// Round 6
// baseline (30241.525 us; speedup 1.0000x reference)
//
#include <hip/hip_runtime.h>

// Round 6: fix R5's weight-spill. LSTM2 = 2 WGs x 16 samples (m=16), 4 layers
// pipelined in-CU via LDS, one barrier/tick, zero fences.
//  - __launch_bounds__(1024, 4): VGPR cap 512 so 64 B-frags (256 VGPR) stay
//    register-resident (R5's cap-64 forced L2 streaming = 10x).
//  - gate-local col mapping: wave wl owns all 4 gates of cells [wl*32,+32) ->
//    epilogue reads i,f,g,o from its own acc regs; no gates[] LDS, 1 barrier.

typedef short    bf16x8 __attribute__((ext_vector_type(8)));
typedef _Float16 f16x8  __attribute__((ext_vector_type(8)));
typedef float    f32x4  __attribute__((ext_vector_type(4)));

#define DEVI static __device__ __forceinline__

constexpr int   T1c   = 20;
constexpr int   EMBc  = 32;
constexpr int   H1c   = 64;
constexpr int   H2c   = 128;
constexpr int   LMAXc = 1024;
constexpr int   Ntot  = 24832;           // sum of lengths
constexpr int   NTc   = Ntot * T1c;      // 496640
constexpr int   R2c   = 32 * LMAXc;      // 32768
constexpr float EPSc  = 1e-5f;

DEVI unsigned short f2bf(float x) {      // RNE float->bf16
    unsigned u = __float_as_uint(x);
    u += 0x7FFFu + ((u >> 16) & 1u);
    return (unsigned short)(u >> 16);
}
DEVI float bf2f(unsigned short h) { return __uint_as_float((unsigned)h << 16); }
DEVI void split2(float x, unsigned short &hi, unsigned short &lo) {
    hi = f2bf(x);
    lo = f2bf(x - bf2f(hi));
}
DEVI float sigm(float x)   { return 1.f / (1.f + __expf(-x)); }
DEVI float tanhf_(float x) { return 1.f - 2.f / (1.f + __expf(2.f * x)); }

// ---------------- weight prep: f32 -> (hi,lo) bf16 (LSTM1)
__global__ void __launch_bounds__(256)
k_prep(const float* __restrict__ in, unsigned short* __restrict__ hi,
       unsigned short* __restrict__ lo, int R, int K, int OS, int KO)
{
    int i = blockIdx.x * 256 + threadIdx.x;
    if (i >= R * K) return;
    int r = i / K, k = i - r * K;
    unsigned short h, l; split2(in[i], h, l);
    hi[r * OS + KO + k] = h;
    lo[r * OS + KO + k] = l;
}

// ---------------- weight prep: f32 -> fp16 with row stride / col offset (LSTM2)
__global__ void __launch_bounds__(256)
k_prep16s(const float* __restrict__ in, _Float16* __restrict__ out,
          int R, int K, int OS, int KO)
{
    int i = blockIdx.x * 256 + threadIdx.x;
    if (i >= R * K) return;
    int r = i / K, k = i - r * K;
    out[(size_t)r * OS + KO + k] = (_Float16)in[i];
}

// ---------------- embedding: x = embed_w[id] * id, split into seq1 (row stride 64)
__global__ void __launch_bounds__(256)
k_embed(const int* __restrict__ atoms, const float* __restrict__ ew,
        unsigned short* __restrict__ shi, unsigned short* __restrict__ slo)
{
    int i = blockIdx.x * 256 + threadIdx.x;
    if (i >= NTc * EMBc) return;
    int nt = i / EMBc, e = i - nt * EMBc;
    int id = atoms[nt];
    float v = ew[id * EMBc + e] * (float)id;
    unsigned short h, l; split2(v, h, l);
    shi[nt * H1c + e] = h;
    slo[nt * H1c + e] = l;
}

// ---------------- LSTM1 scan (unchanged)
template <int KIN>
__global__ void __launch_bounds__(256)
k_scan1(unsigned short* seq_hi, unsigned short* seq_lo,
        const unsigned short* __restrict__ Whi, const unsigned short* __restrict__ Wlo,
        const float* __restrict__ bptr, float* __restrict__ dacc,
        int accum, int writeSeq)
{
    constexpr int KTOT = KIN + 64;
    constexpr int KCH  = KTOT / 32;
    constexpr int SX   = KTOT + 8;
    __shared__ alignas(16) unsigned short xh_hi[32 * SX];
    __shared__ alignas(16) unsigned short xh_lo[32 * SX];

    const int tid  = threadIdx.x;
    const int lane = tid & 63;
    const int wv   = tid >> 6;
    const int l16  = lane & 15;
    const int quad = lane >> 4;
    const int n0   = blockIdx.x * 32;
    const int d    = wv * 16 + l16;

    float bias[4];
#pragma unroll
    for (int g = 0; g < 4; ++g) bias[g] = bptr[g * 64 + d];

    bf16x8 wbh[KCH][4], wbl[KCH][4];
#pragma unroll
    for (int kc = 0; kc < KCH; ++kc) {
        const int kb = kc * 32 + quad * 8;
#pragma unroll
        for (int g = 0; g < 4; ++g) {
            const int j = g * 64 + d;
            wbh[kc][g] = *(const bf16x8*)&Whi[j * 128 + kb];
            wbl[kc][g] = *(const bf16x8*)&Wlo[j * 128 + kb];
        }
    }

    f32x4 c[2];
    c[0] = {1.f, 1.f, 1.f, 1.f};
    c[1] = {1.f, 1.f, 1.f, 1.f};

#pragma unroll
    for (int mt = 0; mt < 2; ++mt)
#pragma unroll
        for (int r = 0; r < 4; ++r) {
            int s = mt * 16 + quad * 4 + r;
            xh_hi[s * SX + KIN + d] = 0x3F80;
            xh_lo[s * SX + KIN + d] = 0;
        }

#pragma unroll 1
    for (int t = 0; t < T1c; ++t) {
        for (int idx = tid; idx < 32 * KIN; idx += 256) {
            int s = idx / KIN, k = idx - s * KIN;
            int row = (n0 + s) * T1c + t;
            xh_hi[s * SX + k] = seq_hi[row * H1c + k];
            xh_lo[s * SX + k] = seq_lo[row * H1c + k];
        }
        __syncthreads();

        f32x4 acc[2][4];
#pragma unroll
        for (int mt = 0; mt < 2; ++mt)
#pragma unroll
            for (int g = 0; g < 4; ++g)
                acc[mt][g] = {bias[g], bias[g], bias[g], bias[g]};

#pragma unroll
        for (int kc = 0; kc < KCH; ++kc) {
            const int kb = kc * 32 + quad * 8;
            bf16x8 ah[2], al[2];
#pragma unroll
            for (int mt = 0; mt < 2; ++mt) {
                const int ro = (mt * 16 + l16) * SX + kb;
                ah[mt] = *(const bf16x8*)&xh_hi[ro];
                al[mt] = *(const bf16x8*)&xh_lo[ro];
            }
#pragma unroll
            for (int g = 0; g < 4; ++g)
#pragma unroll
                for (int mt = 0; mt < 2; ++mt) {
                    acc[mt][g] = __builtin_amdgcn_mfma_f32_16x16x32_bf16(ah[mt], wbh[kc][g], acc[mt][g], 0, 0, 0);
                    acc[mt][g] = __builtin_amdgcn_mfma_f32_16x16x32_bf16(ah[mt], wbl[kc][g], acc[mt][g], 0, 0, 0);
                    acc[mt][g] = __builtin_amdgcn_mfma_f32_16x16x32_bf16(al[mt], wbh[kc][g], acc[mt][g], 0, 0, 0);
                }
        }
        __syncthreads();

#pragma unroll
        for (int mt = 0; mt < 2; ++mt)
#pragma unroll
            for (int r = 0; r < 4; ++r) {
                float iv = sigm(acc[mt][0][r]);
                float fv = sigm(acc[mt][1][r]);
                float gv = tanhf_(acc[mt][2][r]);
                float ov = sigm(acc[mt][3][r]);
                float cv = fv * c[mt][r] + iv * gv;
                c[mt][r] = cv;
                float hv = ov * tanhf_(cv);
                unsigned short hh, hl; split2(hv, hh, hl);
                int s = mt * 16 + quad * 4 + r;
                xh_hi[s * SX + KIN + d] = hh;
                xh_lo[s * SX + KIN + d] = hl;
                if (writeSeq) {
                    int row = (n0 + s) * T1c + t;
                    seq_hi[row * H1c + d] = hh;
                    seq_lo[row * H1c + d] = hl;
                }
                if (t == T1c - 1) {
                    int o = (n0 + s) * H1c + d;
                    float val = 0.25f * (hv + cv);
                    if (accum) dacc[o] += val; else dacc[o] = val;
                }
            }
    }
}

// ---------------- BN2 stats (unchanged)
__global__ void __launch_bounds__(256)
k_bn2_stats(const int* __restrict__ lens, const float* __restrict__ dacc,
            float* __restrict__ stats)
{
    int b = blockIdx.x;
    int off = 0;
    for (int i = 0; i < b; ++i) off += lens[i];
    int len = lens[b];
    const float* base = dacc + (long)off * H1c;
    float s = 0.f, ss = 0.f;
    int total = len * H1c;
    for (int i = threadIdx.x; i < total; i += 256) { float v = base[i]; s += v; ss += v * v; }
    __shared__ float rs[256], rss[256];
    rs[threadIdx.x] = s; rss[threadIdx.x] = ss;
    __syncthreads();
    for (int st = 128; st > 0; st >>= 1) {
        if (threadIdx.x < st) { rs[threadIdx.x] += rs[threadIdx.x + st]; rss[threadIdx.x] += rss[threadIdx.x + st]; }
        __syncthreads();
    }
    if (threadIdx.x == 0) {
        float m = rs[0] / (float)(LMAXc * H1c);
        float v = rss[0] / (float)(LMAXc * H1c) - m * m;
        stats[b]      = m;
        stats[32 + b] = rsqrtf(fmaxf(v, 0.f) + EPSc);
        stats[64 + b] = (float)off;
    }
}

// ---------------- BN2 apply -> LSTM2 layer-0 input, fp16, rows (t*32+b) of 128
// halves: cols [0,64) = BN output, cols [64,128) = exact zero (weight pad).
__global__ void __launch_bounds__(256)
k_bn2_apply(const float* __restrict__ dacc, const float* __restrict__ stats,
            const int* __restrict__ lens, const float* __restrict__ g,
            const float* __restrict__ bb, _Float16* __restrict__ outA)
{
    int i = blockIdx.x * 256 + threadIdx.x;
    if (i >= R2c * 128) return;
    int rr = i >> 7, k = i & 127;
    int b = rr >> 10, p = rr & 1023;
    float y = 0.f;
    if (k < H1c) {
        int off = (int)stats[64 + b];
        float x = (p < lens[b]) ? dacc[(off + p) * H1c + k] : 0.f;
        y = (x - stats[b]) * stats[32 + b] * g[b] + bb[b];
    }
    outA[(size_t)(p * 32 + b) * 128 + k] = (_Float16)y;
}

// ---------------- LSTM2: 2 WGs x 16 samples; 16 waves = 4 layers x 4 waves.
// Tick u: layer l computes t=u-l.  av[l][parity] = 16 rows x [x(128)|h(128)]
// fp16 (row pad to 264).  Wave wl owns all 4 gates of cells [wl*32, wl*32+32):
// acc[nt], nt = g*2+ch -> col (nt>>1)*128 + wl*32 + (nt&1)*16 + l16.
// Epilogue is register-local; ONE barrier per tick.
__global__ void __launch_bounds__(1024, 4)
k_scan2b(const _Float16* __restrict__ seqA,   // (t*32+b) rows x 128 halves
         const _Float16* __restrict__ wcomb,  // [4][512][256] fp16
         const float* __restrict__ b0, const float* __restrict__ bS,
         float* __restrict__ c2)              // [4][32][128]
{
    constexpr int SH2 = 264;                  // 16B-aligned row pad (2-way banks)
    __shared__ alignas(16) _Float16 av[4][2][16 * SH2];   // 67.6 KB

    const int S0   = blockIdx.x * 16;         // first sample of this WG
    const int tid  = threadIdx.x;
    const int lane = tid & 63;
    const int wv   = tid >> 6;                // 0..15
    const int l    = wv >> 2;                 // layer
    const int wl   = wv & 3;                  // wave within layer
    const int l16  = lane & 15, quad = lane >> 4;

    // register-resident weights: 64 f16x8 = 256 VGPRs (cap 512 via launch_bounds)
    f16x8 wB[8][8];
    {
        const _Float16* W = wcomb + (size_t)l * 512 * 256;
#pragma unroll
        for (int nt = 0; nt < 8; ++nt) {
            const int col = (nt >> 1) * 128 + wl * 32 + (nt & 1) * 16 + l16;
#pragma unroll
            for (int kc = 0; kc < 8; ++kc)
                wB[nt][kc] = *(const f16x8*)&W[(size_t)col * 256 + kc * 32 + quad * 8];
        }
    }

    float bias[8];                            // [g*2+ch]
    {
        const float* bp = (l == 0) ? b0 : bS + (l - 1) * 512;
#pragma unroll
        for (int g = 0; g < 4; ++g)
#pragma unroll
            for (int ch = 0; ch < 2; ++ch)
                bias[g * 2 + ch] = bp[g * 128 + wl * 32 + ch * 16 + l16];
    }

    float cst[2][4];
#pragma unroll
    for (int ch = 0; ch < 2; ++ch)
#pragma unroll
        for (int r = 0; r < 4; ++r) cst[ch][r] = 1.f;

    for (int i = tid; i < 4 * 2 * 16 * SH2; i += 1024)
        ((_Float16*)av)[i] = (_Float16)0.f;
    __syncthreads();
    {   // h init = 1.0 at each layer's first read-parity
        const int pr0 = (l + 1) & 1;
#pragma unroll
        for (int ch = 0; ch < 2; ++ch)
#pragma unroll
            for (int r = 0; r < 4; ++r) {
                const int s = quad * 4 + r, c = wl * 32 + ch * 16 + l16;
                av[l][pr0][s * SH2 + 128 + c] = (_Float16)1.0f;
            }
    }
    if (wv == 15) {                           // stage layer-0 x(t=0) into parity 1
        const int s = lane >> 2, chk = lane & 3;
        const f16x8* src = (const f16x8*)&seqA[(size_t)(S0 + s) * 128 + chk * 32];
#pragma unroll
        for (int i = 0; i < 4; ++i)
            *(f16x8*)&av[0][1][s * SH2 + chk * 32 + i * 8] = src[i];
    }
    __syncthreads();

#pragma unroll 1
    for (int u = 0; u < LMAXc + 3; ++u) {
        const int  t   = u - l;
        const bool act = (t >= 0) && (t < LMAXc);
        const int  pw  = u & 1, pr = pw ^ 1;

        // staging loads issued at tick top (~5k cyc to hide)
        f16x8 xs[4];
        const bool doStage = (wv == 15) && (u + 1 < LMAXc);
        if (doStage) {
            const int s = lane >> 2, chk = lane & 3;
            const f16x8* src = (const f16x8*)&seqA[(size_t)((u + 1) * 32 + S0 + s) * 128 + chk * 32];
#pragma unroll
            for (int i = 0; i < 4; ++i) xs[i] = src[i];
        }

        if (act) {
            f16x8 af[8];
#pragma unroll
            for (int kc = 0; kc < 8; ++kc)
                af[kc] = *(const f16x8*)&av[l][pr][l16 * SH2 + kc * 32 + quad * 8];
            f32x4 acc[8];
#pragma unroll
            for (int nt = 0; nt < 8; ++nt) acc[nt] = {0.f, 0.f, 0.f, 0.f};
#pragma unroll
            for (int kc = 0; kc < 8; ++kc)
#pragma unroll
                for (int nt = 0; nt < 8; ++nt)
                    acc[nt] = __builtin_amdgcn_mfma_f32_16x16x32_f16(af[kc], wB[nt][kc], acc[nt], 0, 0, 0);

            // register-local epilogue: lane has i,f,g,o for its 2 cells x 4 samples
#pragma unroll
            for (int ch = 0; ch < 2; ++ch)
#pragma unroll
                for (int r = 0; r < 4; ++r) {
                    float iv = sigm(acc[0 + ch][r] + bias[0 + ch]);
                    float fv = sigm(acc[2 + ch][r] + bias[2 + ch]);
                    float gv = tanhf_(acc[4 + ch][r] + bias[4 + ch]);
                    float ov = sigm(acc[6 + ch][r] + bias[6 + ch]);
                    float cv = fv * cst[ch][r] + iv * gv;
                    cst[ch][r] = cv;
                    float hv = ov * tanhf_(cv);
                    _Float16 hf = (_Float16)hv;
                    const int s = quad * 4 + r, c = wl * 32 + ch * 16 + l16;
                    av[l][pw][s * SH2 + 128 + c] = hf;
                    if (l < 3) av[l + 1][pw][s * SH2 + c] = hf;
                    if (t == LMAXc - 1)
                        c2[(size_t)(l * 32 + S0 + s) * 128 + c] = 0.25f * cv;
                }
        }
        if (doStage) {
            const int s = lane >> 2, chk = lane & 3;
#pragma unroll
            for (int i = 0; i < 4; ++i)
                *(f16x8*)&av[0][pw][s * SH2 + chk * 32 + i * 8] = xs[i];
        }
        __syncthreads();
    }
}

// ---------------- head: BN3 + MLP + relu(sum), single WG fp32
DEVI void bn_rows_dev(float* X, int K, const float* g, const float* bb,
                      float* mv, int tid)
{
    __syncthreads();
    if (tid < 32) {
        float s = 0.f, ss = 0.f;
        const float* r = X + tid * K;
        for (int k = 0; k < K; ++k) { float v = r[k]; s += v; ss += v * v; }
        float m = s / (float)K;
        float vv = ss / (float)K - m * m;
        mv[tid]      = m;
        mv[32 + tid] = rsqrtf(fmaxf(vv, 0.f) + EPSc);
    }
    __syncthreads();
    for (int i = tid; i < 32 * K; i += 256) {
        int b = i / K;
        X[i] = (X[i] - mv[b]) * mv[32 + b] * g[b] + bb[b];
    }
    __syncthreads();
}

DEVI void lin_dev(const float* X, int K, const float* W, const float* bias,
                  int NO, float* Y, int relu, int tid)
{
    __syncthreads();
    for (int i = tid; i < 32 * NO; i += 256) {
        int b = i / NO, j = i - b * NO;
        float a = bias[j];
        const float* xr = X + b * K;
        const float* wr = W + j * K;
        for (int k = 0; k < K; ++k) a += xr[k] * wr[k];
        Y[i] = relu ? fmaxf(a, 0.f) : a;
    }
    __syncthreads();
}

__global__ void __launch_bounds__(256)
k_head(const float* __restrict__ c2, const float* __restrict__ g3, const float* __restrict__ bb3,
       const float* w1, const float* b1, const float* w2, const float* b2,
       const float* w22, const float* b22, const float* w3, const float* b3,
       const float* w4, const float* b4, const float* w5, const float* b5,
       float* __restrict__ out)
{
    __shared__ float A[32 * 128];
    __shared__ float Bf[32 * 128];
    __shared__ float mv[64];
    const int tid = threadIdx.x;

    for (int i = tid; i < 32 * 128; i += 256)
        A[i] = c2[i] + c2[4096 + i] + c2[8192 + i] + c2[12288 + i];
    bn_rows_dev(A, 128, g3, bb3, mv, tid);
    lin_dev(A, 128, w1, b1, 128, Bf, 1, tid);
    lin_dev(Bf, 128, w2, b2, 64, A, 1, tid);
    bn_rows_dev(A, 64, g3, bb3, mv, tid);
    lin_dev(A, 64, w22, b22, 64, Bf, 1, tid);
    lin_dev(Bf, 64, w3, b3, 32, A, 1, tid);
    lin_dev(A, 32, w4, b4, 32, Bf, 1, tid);
    lin_dev(Bf, 32, w5, b5, 16, A, 0, tid);
    if (tid < 32) {
        float s = 0.f;
        for (int j = 0; j < 16; ++j) s += A[tid * 16 + j];
        out[tid] = fmaxf(s, 0.f);
    }
}

// ---------------- host
extern "C" void kernel_launch(void* const* d_in, const int* in_sizes, int n_in,
                              void* d_out, int out_size, void* d_ws, size_t ws_size,
                              hipStream_t stream)
{
    const int*   atoms  = (const int*)d_in[0];
    const int*   lens   = (const int*)d_in[2];
    const float* embw   = (const float*)d_in[5];
    const float* l1Wih0 = (const float*)d_in[6];
    const float* l1Whh0 = (const float*)d_in[7];
    const float* l1b0   = (const float*)d_in[8];
    const float* l1Wih  = (const float*)d_in[9];
    const float* l1Whh  = (const float*)d_in[10];
    const float* l1b    = (const float*)d_in[11];
    const float* l2Wih0 = (const float*)d_in[12];
    const float* l2Whh0 = (const float*)d_in[13];
    const float* l2b0   = (const float*)d_in[14];
    const float* l2Wih  = (const float*)d_in[15];
    const float* l2Whh  = (const float*)d_in[16];
    const float* l2b    = (const float*)d_in[17];
    const float* bn2g   = (const float*)d_in[18];
    const float* bn2b   = (const float*)d_in[19];
    const float* bn3g   = (const float*)d_in[20];
    const float* bn3b   = (const float*)d_in[21];
    const float* w1  = (const float*)d_in[22]; const float* b1  = (const float*)d_in[23];
    const float* w2  = (const float*)d_in[24]; const float* b2  = (const float*)d_in[25];
    const float* w22 = (const float*)d_in[26]; const float* b22 = (const float*)d_in[27];
    const float* w3  = (const float*)d_in[28]; const float* b3  = (const float*)d_in[29];
    const float* w4  = (const float*)d_in[30]; const float* b4  = (const float*)d_in[31];
    const float* w5  = (const float*)d_in[32]; const float* b5  = (const float*)d_in[33];
    float* out = (float*)d_out;

    char* base = (char*)d_ws;
    size_t off = 0;
    auto take = [&](size_t bytes) -> char* {
        char* p = base + off;
        off = (off + bytes + 255) & ~(size_t)255;
        return p;
    };
    unsigned short* seq1h  = (unsigned short*)take((size_t)NTc * H1c * 2);   // 63.6 MB
    unsigned short* seq1l  = (unsigned short*)take((size_t)NTc * H1c * 2);
    float*          dacc   = (float*)take((size_t)Ntot * H1c * 4);           // 6.4 MB
    unsigned short* w1h    = (unsigned short*)take((size_t)4 * 256 * 128 * 2);
    unsigned short* w1l    = (unsigned short*)take((size_t)4 * 256 * 128 * 2);
    _Float16*       wcomb  = (_Float16*)take((size_t)4 * 512 * 256 * 2);     // 1 MB
    _Float16*       seqA   = (_Float16*)take((size_t)R2c * 128 * 2);         // 8.4 MB
    float*          stats  = (float*)take(1024);
    float*          c2     = (float*)take((size_t)4 * 32 * 128 * 4);

    auto prep = [&](const float* src, unsigned short* dh, unsigned short* dl,
                    int R, int K, int OS, int KO) {
        int n = R * K;
        k_prep<<<(n + 255) / 256, 256, 0, stream>>>(src, dh, dl, R, K, OS, KO);
    };
    auto prep16 = [&](const float* src, _Float16* dst, int R, int K, int OS, int KO) {
        int n = R * K;
        k_prep16s<<<(n + 255) / 256, 256, 0, stream>>>(src, dst, R, K, OS, KO);
    };

    // LSTM1 combined [Wih | Whh] split-bf16, row stride 128
    prep(l1Wih0, w1h, w1l, 256, 32, 128, 0);
    prep(l1Whh0, w1h, w1l, 256, 64, 128, 32);
    for (int l = 1; l < 4; ++l) {
        prep(l1Wih + (l - 1) * 256 * 64, w1h + l * 256 * 128, w1l + l * 256 * 128, 256, 64, 128, 0);
        prep(l1Whh + (l - 1) * 256 * 64, w1h + l * 256 * 128, w1l + l * 256 * 128, 256, 64, 128, 64);
    }
    // LSTM2 combined fp16 [Wih (zero-padded to 128) | Whh], row stride 256
    hipMemsetAsync(wcomb, 0, (size_t)4 * 512 * 256 * 2, stream);
    prep16(l2Wih0, wcomb, 512, 64, 256, 0);
    prep16(l2Whh0, wcomb, 512, 128, 256, 128);
    for (int l = 1; l < 4; ++l) {
        prep16(l2Wih + (l - 1) * 512 * 128, wcomb + (size_t)l * 512 * 256, 512, 128, 256, 0);
        prep16(l2Whh + (l - 1) * 512 * 128, wcomb + (size_t)l * 512 * 256, 512, 128, 256, 128);
    }

    k_embed<<<(NTc * EMBc + 255) / 256, 256, 0, stream>>>(atoms, embw, seq1h, seq1l);

    for (int l = 0; l < 4; ++l) {
        const float* bp = (l == 0) ? l1b0 : l1b + (l - 1) * 256;
        if (l == 0)
            k_scan1<32><<<Ntot / 32, 256, 0, stream>>>(seq1h, seq1l, w1h, w1l, bp, dacc, 0, 1);
        else
            k_scan1<64><<<Ntot / 32, 256, 0, stream>>>(seq1h, seq1l,
                                                       w1h + l * 256 * 128, w1l + l * 256 * 128,
                                                       bp, dacc, 1, (l != 3) ? 1 : 0);
    }

    k_bn2_stats<<<32, 256, 0, stream>>>(lens, dacc, stats);
    k_bn2_apply<<<(R2c * 128 + 255) / 256, 256, 0, stream>>>(dacc, stats, lens, bn2g, bn2b, seqA);

    k_scan2b<<<2, 1024, 0, stream>>>(seqA, wcomb, l2b0, l2b, c2);

    k_head<<<1, 256, 0, stream>>>(c2, bn3g, bn3b, w1, b1, w2, b2, w22, b22,
                                  w3, b3, w4, b4, w5, b5, out);

    (void)in_sizes; (void)n_in; (void)out_size; (void)ws_size;
}

// Round 7
// 5554.689 us; speedup vs baseline: 5.4443x; 5.4443x over previous
//
#include <hip/hip_runtime.h>

// Round 7: LSTM2 = batch decomposition. 8 WGs x 4 samples; each WG does the 4
// layer passes SERIALLY for its samples (no cross-WG sync at all; h-seq in
// WG-private global ping-pong). Register law honored: 512 VGPR/SIMD pool ->
// 8-wave WG (2/SIMD) with __launch_bounds__(512,2) gives 256 VGPR cap; per
// wave: 128 weight VGPRs (its 64 gate-cols x K=256 fp16) + ~90 working.
// Epilogue: 1 cell/lane (quad = sample via cndmask select), 1 barrier/step.

typedef short    bf16x8 __attribute__((ext_vector_type(8)));
typedef _Float16 f16x8  __attribute__((ext_vector_type(8)));
typedef float    f32x4  __attribute__((ext_vector_type(4)));

#define DEVI static __device__ __forceinline__

constexpr int   T1c   = 20;
constexpr int   EMBc  = 32;
constexpr int   H1c   = 64;
constexpr int   H2c   = 128;
constexpr int   LMAXc = 1024;
constexpr int   Ntot  = 24832;           // sum of lengths
constexpr int   NTc   = Ntot * T1c;      // 496640
constexpr int   R2c   = 32 * LMAXc;      // 32768
constexpr float EPSc  = 1e-5f;

DEVI unsigned short f2bf(float x) {      // RNE float->bf16
    unsigned u = __float_as_uint(x);
    u += 0x7FFFu + ((u >> 16) & 1u);
    return (unsigned short)(u >> 16);
}
DEVI float bf2f(unsigned short h) { return __uint_as_float((unsigned)h << 16); }
DEVI void split2(float x, unsigned short &hi, unsigned short &lo) {
    hi = f2bf(x);
    lo = f2bf(x - bf2f(hi));
}
DEVI float sigm(float x)   { return 1.f / (1.f + __expf(-x)); }
DEVI float tanhf_(float x) { return 1.f - 2.f / (1.f + __expf(2.f * x)); }

// ---------------- weight prep: f32 -> (hi,lo) bf16 (LSTM1)
__global__ void __launch_bounds__(256)
k_prep(const float* __restrict__ in, unsigned short* __restrict__ hi,
       unsigned short* __restrict__ lo, int R, int K, int OS, int KO)
{
    int i = blockIdx.x * 256 + threadIdx.x;
    if (i >= R * K) return;
    int r = i / K, k = i - r * K;
    unsigned short h, l; split2(in[i], h, l);
    hi[r * OS + KO + k] = h;
    lo[r * OS + KO + k] = l;
}

// ---------------- weight prep: f32 -> fp16 with row stride / col offset (LSTM2)
__global__ void __launch_bounds__(256)
k_prep16s(const float* __restrict__ in, _Float16* __restrict__ out,
          int R, int K, int OS, int KO)
{
    int i = blockIdx.x * 256 + threadIdx.x;
    if (i >= R * K) return;
    int r = i / K, k = i - r * K;
    out[(size_t)r * OS + KO + k] = (_Float16)in[i];
}

// ---------------- embedding: x = embed_w[id] * id, split into seq1 (row stride 64)
__global__ void __launch_bounds__(256)
k_embed(const int* __restrict__ atoms, const float* __restrict__ ew,
        unsigned short* __restrict__ shi, unsigned short* __restrict__ slo)
{
    int i = blockIdx.x * 256 + threadIdx.x;
    if (i >= NTc * EMBc) return;
    int nt = i / EMBc, e = i - nt * EMBc;
    int id = atoms[nt];
    float v = ew[id * EMBc + e] * (float)id;
    unsigned short h, l; split2(v, h, l);
    shi[nt * H1c + e] = h;
    slo[nt * H1c + e] = l;
}

// ---------------- LSTM1 scan (unchanged)
template <int KIN>
__global__ void __launch_bounds__(256)
k_scan1(unsigned short* seq_hi, unsigned short* seq_lo,
        const unsigned short* __restrict__ Whi, const unsigned short* __restrict__ Wlo,
        const float* __restrict__ bptr, float* __restrict__ dacc,
        int accum, int writeSeq)
{
    constexpr int KTOT = KIN + 64;
    constexpr int KCH  = KTOT / 32;
    constexpr int SX   = KTOT + 8;
    __shared__ alignas(16) unsigned short xh_hi[32 * SX];
    __shared__ alignas(16) unsigned short xh_lo[32 * SX];

    const int tid  = threadIdx.x;
    const int lane = tid & 63;
    const int wv   = tid >> 6;
    const int l16  = lane & 15;
    const int quad = lane >> 4;
    const int n0   = blockIdx.x * 32;
    const int d    = wv * 16 + l16;

    float bias[4];
#pragma unroll
    for (int g = 0; g < 4; ++g) bias[g] = bptr[g * 64 + d];

    bf16x8 wbh[KCH][4], wbl[KCH][4];
#pragma unroll
    for (int kc = 0; kc < KCH; ++kc) {
        const int kb = kc * 32 + quad * 8;
#pragma unroll
        for (int g = 0; g < 4; ++g) {
            const int j = g * 64 + d;
            wbh[kc][g] = *(const bf16x8*)&Whi[j * 128 + kb];
            wbl[kc][g] = *(const bf16x8*)&Wlo[j * 128 + kb];
        }
    }

    f32x4 c[2];
    c[0] = {1.f, 1.f, 1.f, 1.f};
    c[1] = {1.f, 1.f, 1.f, 1.f};

#pragma unroll
    for (int mt = 0; mt < 2; ++mt)
#pragma unroll
        for (int r = 0; r < 4; ++r) {
            int s = mt * 16 + quad * 4 + r;
            xh_hi[s * SX + KIN + d] = 0x3F80;
            xh_lo[s * SX + KIN + d] = 0;
        }

#pragma unroll 1
    for (int t = 0; t < T1c; ++t) {
        for (int idx = tid; idx < 32 * KIN; idx += 256) {
            int s = idx / KIN, k = idx - s * KIN;
            int row = (n0 + s) * T1c + t;
            xh_hi[s * SX + k] = seq_hi[row * H1c + k];
            xh_lo[s * SX + k] = seq_lo[row * H1c + k];
        }
        __syncthreads();

        f32x4 acc[2][4];
#pragma unroll
        for (int mt = 0; mt < 2; ++mt)
#pragma unroll
            for (int g = 0; g < 4; ++g)
                acc[mt][g] = {bias[g], bias[g], bias[g], bias[g]};

#pragma unroll
        for (int kc = 0; kc < KCH; ++kc) {
            const int kb = kc * 32 + quad * 8;
            bf16x8 ah[2], al[2];
#pragma unroll
            for (int mt = 0; mt < 2; ++mt) {
                const int ro = (mt * 16 + l16) * SX + kb;
                ah[mt] = *(const bf16x8*)&xh_hi[ro];
                al[mt] = *(const bf16x8*)&xh_lo[ro];
            }
#pragma unroll
            for (int g = 0; g < 4; ++g)
#pragma unroll
                for (int mt = 0; mt < 2; ++mt) {
                    acc[mt][g] = __builtin_amdgcn_mfma_f32_16x16x32_bf16(ah[mt], wbh[kc][g], acc[mt][g], 0, 0, 0);
                    acc[mt][g] = __builtin_amdgcn_mfma_f32_16x16x32_bf16(ah[mt], wbl[kc][g], acc[mt][g], 0, 0, 0);
                    acc[mt][g] = __builtin_amdgcn_mfma_f32_16x16x32_bf16(al[mt], wbh[kc][g], acc[mt][g], 0, 0, 0);
                }
        }
        __syncthreads();

#pragma unroll
        for (int mt = 0; mt < 2; ++mt)
#pragma unroll
            for (int r = 0; r < 4; ++r) {
                float iv = sigm(acc[mt][0][r]);
                float fv = sigm(acc[mt][1][r]);
                float gv = tanhf_(acc[mt][2][r]);
                float ov = sigm(acc[mt][3][r]);
                float cv = fv * c[mt][r] + iv * gv;
                c[mt][r] = cv;
                float hv = ov * tanhf_(cv);
                unsigned short hh, hl; split2(hv, hh, hl);
                int s = mt * 16 + quad * 4 + r;
                xh_hi[s * SX + KIN + d] = hh;
                xh_lo[s * SX + KIN + d] = hl;
                if (writeSeq) {
                    int row = (n0 + s) * T1c + t;
                    seq_hi[row * H1c + d] = hh;
                    seq_lo[row * H1c + d] = hl;
                }
                if (t == T1c - 1) {
                    int o = (n0 + s) * H1c + d;
                    float val = 0.25f * (hv + cv);
                    if (accum) dacc[o] += val; else dacc[o] = val;
                }
            }
    }
}

// ---------------- BN2 stats (unchanged)
__global__ void __launch_bounds__(256)
k_bn2_stats(const int* __restrict__ lens, const float* __restrict__ dacc,
            float* __restrict__ stats)
{
    int b = blockIdx.x;
    int off = 0;
    for (int i = 0; i < b; ++i) off += lens[i];
    int len = lens[b];
    const float* base = dacc + (long)off * H1c;
    float s = 0.f, ss = 0.f;
    int total = len * H1c;
    for (int i = threadIdx.x; i < total; i += 256) { float v = base[i]; s += v; ss += v * v; }
    __shared__ float rs[256], rss[256];
    rs[threadIdx.x] = s; rss[threadIdx.x] = ss;
    __syncthreads();
    for (int st = 128; st > 0; st >>= 1) {
        if (threadIdx.x < st) { rs[threadIdx.x] += rs[threadIdx.x + st]; rss[threadIdx.x] += rss[threadIdx.x + st]; }
        __syncthreads();
    }
    if (threadIdx.x == 0) {
        float m = rs[0] / (float)(LMAXc * H1c);
        float v = rss[0] / (float)(LMAXc * H1c) - m * m;
        stats[b]      = m;
        stats[32 + b] = rsqrtf(fmaxf(v, 0.f) + EPSc);
        stats[64 + b] = (float)off;
    }
}

// ---------------- BN2 apply -> LSTM2 layer-0 input, fp16, rows (t*32+b) of 128
// halves: cols [0,64) = BN output, cols [64,128) = exact zero (weight pad).
__global__ void __launch_bounds__(256)
k_bn2_apply(const float* __restrict__ dacc, const float* __restrict__ stats,
            const int* __restrict__ lens, const float* __restrict__ g,
            const float* __restrict__ bb, _Float16* __restrict__ outA)
{
    int i = blockIdx.x * 256 + threadIdx.x;
    if (i >= R2c * 128) return;
    int rr = i >> 7, k = i & 127;
    int b = rr >> 10, p = rr & 1023;
    float y = 0.f;
    if (k < H1c) {
        int off = (int)stats[64 + b];
        float x = (p < lens[b]) ? dacc[(off + p) * H1c + k] : 0.f;
        y = (x - stats[b]) * stats[32 + b] * g[b] + bb[b];
    }
    outA[(size_t)(p * 32 + b) * 128 + k] = (_Float16)y;
}

DEVI float qsel(f32x4 a, int quad) {     // a[quad] without scratch
    float t01 = (quad & 1) ? a[1] : a[0];
    float t23 = (quad & 1) ? a[3] : a[2];
    return (quad & 2) ? t23 : t01;
}

// ---------------- LSTM2: 8 WGs x 4 samples, 4 layer passes serial per WG.
// 512 thr = 8 waves (2/SIMD, VGPR cap 256). Wave w owns cells [w*16,w*16+16):
// its 4 n-tiles are cols {g*128 + w*16}, so lane (w,quad,l16) ends up with all
// 4 gate values of cell w*16+l16 for sample=quad (one cndmask-select away).
// A rows replicated via (l16&3) broadcast reads. One barrier per step.
__global__ void __launch_bounds__(512, 2)
k_scan2c(const _Float16* __restrict__ seqA,   // (t*32+b) rows x 128 halves
         const _Float16* __restrict__ wcomb,  // [4][512][256] fp16
         const float* __restrict__ b0, const float* __restrict__ bS,
         _Float16* __restrict__ hseq,         // [8 WG][2][1024*4*128] ping-pong
         float* __restrict__ c2)              // [4][32][128]
{
    constexpr int SH = 264;                   // halves per row (16B-aligned pad)
    __shared__ alignas(16) _Float16 av[2][4 * SH];   // [parity][sample][x(128)|h(128)]

    const int S0   = blockIdx.x * 4;
    const int tid  = threadIdx.x;
    const int lane = tid & 63;
    const int w    = tid >> 6;                // wave 0..7
    const int l16  = lane & 15, quad = lane >> 4;
    const int cell = w * 16 + l16;            // 0..127

    _Float16* hbufA = hseq + (size_t)blockIdx.x * 2 * LMAXc * 4 * 128;
    _Float16* hbufB = hbufA + (size_t)LMAXc * 4 * 128;

#pragma unroll 1
    for (int l = 0; l < 4; ++l) {
        // ---- per-pass setup
        const _Float16* W  = wcomb + (size_t)l * 512 * 256;
        const float*    bp = (l == 0) ? b0 : bS + (l - 1) * 512;
        const _Float16* xsrc;  size_t xstride;
        if (l == 0) { xsrc = seqA + (size_t)S0 * 128; xstride = 32 * 128; }
        else        { xsrc = (l & 1) ? hbufA : hbufB; xstride = 4 * 128; }
        _Float16* hdst = (l & 1) ? hbufB : hbufA;     // pass l writes, l+1 reads

        f16x8 wB[4][8];                        // 128 VGPRs
#pragma unroll
        for (int g = 0; g < 4; ++g)
#pragma unroll
            for (int kc = 0; kc < 8; ++kc)
                wB[g][kc] = *(const f16x8*)&W[(size_t)(g * 128 + cell) * 256 + kc * 32 + quad * 8];

        float bias[4];
#pragma unroll
        for (int g = 0; g < 4; ++g) bias[g] = bp[g * 128 + cell];

        float cst = 1.f;

        __syncthreads();                       // previous pass fully done
        __threadfence();                       // L1 safety for hseq re-read (4x/kernel)
        // init: h(t=-1)=1 in parity 1; x(0) in parity 1 (wave 7)
        av[1][quad * SH + 128 + cell] = (_Float16)1.0f;
        if (w == 7) {
            const int s = lane >> 4, chk = lane & 15;
            *(f16x8*)&av[1][s * SH + chk * 8] =
                *(const f16x8*)&xsrc[(size_t)0 * xstride + s * 128 + chk * 8];
        }
        __syncthreads();

#pragma unroll 1
        for (int t = 0; t < LMAXc; ++t) {
            const int pw = t & 1, pr = pw ^ 1;

            // prefetch x(t+1) (wave 7; 64 lanes x 16B = 1 KB)
            f16x8 xn;
            const bool doStage = (w == 7) && (t + 1 < LMAXc);
            if (doStage) {
                const int s = lane >> 4, chk = lane & 15;
                xn = *(const f16x8*)&xsrc[(size_t)(t + 1) * xstride + s * 128 + chk * 8];
            }

            // A-frags: rows replicated (l16&3 -> sample), broadcast reads
            f16x8 af[8];
#pragma unroll
            for (int kc = 0; kc < 8; ++kc)
                af[kc] = *(const f16x8*)&av[pr][(l16 & 3) * SH + kc * 32 + quad * 8];

            f32x4 acc[4];
#pragma unroll
            for (int g = 0; g < 4; ++g) acc[g] = {0.f, 0.f, 0.f, 0.f};
#pragma unroll
            for (int kc = 0; kc < 8; ++kc)
#pragma unroll
                for (int g = 0; g < 4; ++g)
                    acc[g] = __builtin_amdgcn_mfma_f32_16x16x32_f16(af[kc], wB[g][kc], acc[g], 0, 0, 0);

            // epilogue: this lane = cell, sample=quad
            float gi = qsel(acc[0], quad) + bias[0];
            float gf = qsel(acc[1], quad) + bias[1];
            float gg = qsel(acc[2], quad) + bias[2];
            float go = qsel(acc[3], quad) + bias[3];
            float cv = sigm(gf) * cst + sigm(gi) * tanhf_(gg);
            cst = cv;
            float hv = sigm(go) * tanhf_(cv);
            _Float16 hf = (_Float16)hv;
            av[pw][quad * SH + 128 + cell] = hf;
            if (l < 3) hdst[(size_t)(t * 4 + quad) * 128 + cell] = hf;
            if (t == LMAXc - 1) c2[(size_t)(l * 32 + S0 + quad) * 128 + cell] = 0.25f * cv;

            if (doStage) {
                const int s = lane >> 4, chk = lane & 15;
                *(f16x8*)&av[pw][s * SH + chk * 8] = xn;
            }
            __syncthreads();
        }
    }
}

// ---------------- head: BN3 + MLP + relu(sum), single WG fp32
DEVI void bn_rows_dev(float* X, int K, const float* g, const float* bb,
                      float* mv, int tid)
{
    __syncthreads();
    if (tid < 32) {
        float s = 0.f, ss = 0.f;
        const float* r = X + tid * K;
        for (int k = 0; k < K; ++k) { float v = r[k]; s += v; ss += v * v; }
        float m = s / (float)K;
        float vv = ss / (float)K - m * m;
        mv[tid]      = m;
        mv[32 + tid] = rsqrtf(fmaxf(vv, 0.f) + EPSc);
    }
    __syncthreads();
    for (int i = tid; i < 32 * K; i += 256) {
        int b = i / K;
        X[i] = (X[i] - mv[b]) * mv[32 + b] * g[b] + bb[b];
    }
    __syncthreads();
}

DEVI void lin_dev(const float* X, int K, const float* W, const float* bias,
                  int NO, float* Y, int relu, int tid)
{
    __syncthreads();
    for (int i = tid; i < 32 * NO; i += 256) {
        int b = i / NO, j = i - b * NO;
        float a = bias[j];
        const float* xr = X + b * K;
        const float* wr = W + j * K;
        for (int k = 0; k < K; ++k) a += xr[k] * wr[k];
        Y[i] = relu ? fmaxf(a, 0.f) : a;
    }
    __syncthreads();
}

__global__ void __launch_bounds__(256)
k_head(const float* __restrict__ c2, const float* __restrict__ g3, const float* __restrict__ bb3,
       const float* w1, const float* b1, const float* w2, const float* b2,
       const float* w22, const float* b22, const float* w3, const float* b3,
       const float* w4, const float* b4, const float* w5, const float* b5,
       float* __restrict__ out)
{
    __shared__ float A[32 * 128];
    __shared__ float Bf[32 * 128];
    __shared__ float mv[64];
    const int tid = threadIdx.x;

    for (int i = tid; i < 32 * 128; i += 256)
        A[i] = c2[i] + c2[4096 + i] + c2[8192 + i] + c2[12288 + i];
    bn_rows_dev(A, 128, g3, bb3, mv, tid);
    lin_dev(A, 128, w1, b1, 128, Bf, 1, tid);
    lin_dev(Bf, 128, w2, b2, 64, A, 1, tid);
    bn_rows_dev(A, 64, g3, bb3, mv, tid);
    lin_dev(A, 64, w22, b22, 64, Bf, 1, tid);
    lin_dev(Bf, 64, w3, b3, 32, A, 1, tid);
    lin_dev(A, 32, w4, b4, 32, Bf, 1, tid);
    lin_dev(Bf, 32, w5, b5, 16, A, 0, tid);
    if (tid < 32) {
        float s = 0.f;
        for (int j = 0; j < 16; ++j) s += A[tid * 16 + j];
        out[tid] = fmaxf(s, 0.f);
    }
}

// ---------------- host
extern "C" void kernel_launch(void* const* d_in, const int* in_sizes, int n_in,
                              void* d_out, int out_size, void* d_ws, size_t ws_size,
                              hipStream_t stream)
{
    const int*   atoms  = (const int*)d_in[0];
    const int*   lens   = (const int*)d_in[2];
    const float* embw   = (const float*)d_in[5];
    const float* l1Wih0 = (const float*)d_in[6];
    const float* l1Whh0 = (const float*)d_in[7];
    const float* l1b0   = (const float*)d_in[8];
    const float* l1Wih  = (const float*)d_in[9];
    const float* l1Whh  = (const float*)d_in[10];
    const float* l1b    = (const float*)d_in[11];
    const float* l2Wih0 = (const float*)d_in[12];
    const float* l2Whh0 = (const float*)d_in[13];
    const float* l2b0   = (const float*)d_in[14];
    const float* l2Wih  = (const float*)d_in[15];
    const float* l2Whh  = (const float*)d_in[16];
    const float* l2b    = (const float*)d_in[17];
    const float* bn2g   = (const float*)d_in[18];
    const float* bn2b   = (const float*)d_in[19];
    const float* bn3g   = (const float*)d_in[20];
    const float* bn3b   = (const float*)d_in[21];
    const float* w1  = (const float*)d_in[22]; const float* b1  = (const float*)d_in[23];
    const float* w2  = (const float*)d_in[24]; const float* b2  = (const float*)d_in[25];
    const float* w22 = (const float*)d_in[26]; const float* b22 = (const float*)d_in[27];
    const float* w3  = (const float*)d_in[28]; const float* b3  = (const float*)d_in[29];
    const float* w4  = (const float*)d_in[30]; const float* b4  = (const float*)d_in[31];
    const float* w5  = (const float*)d_in[32]; const float* b5  = (const float*)d_in[33];
    float* out = (float*)d_out;

    char* base = (char*)d_ws;
    size_t off = 0;
    auto take = [&](size_t bytes) -> char* {
        char* p = base + off;
        off = (off + bytes + 255) & ~(size_t)255;
        return p;
    };
    unsigned short* seq1h  = (unsigned short*)take((size_t)NTc * H1c * 2);   // 63.6 MB
    unsigned short* seq1l  = (unsigned short*)take((size_t)NTc * H1c * 2);
    float*          dacc   = (float*)take((size_t)Ntot * H1c * 4);           // 6.4 MB
    unsigned short* w1h    = (unsigned short*)take((size_t)4 * 256 * 128 * 2);
    unsigned short* w1l    = (unsigned short*)take((size_t)4 * 256 * 128 * 2);
    _Float16*       wcomb  = (_Float16*)take((size_t)4 * 512 * 256 * 2);     // 1 MB
    _Float16*       seqA   = (_Float16*)take((size_t)R2c * 128 * 2);         // 8.4 MB
    _Float16*       hseq   = (_Float16*)take((size_t)8 * 2 * LMAXc * 4 * 128 * 2); // 16.8 MB
    float*          stats  = (float*)take(1024);
    float*          c2     = (float*)take((size_t)4 * 32 * 128 * 4);

    auto prep = [&](const float* src, unsigned short* dh, unsigned short* dl,
                    int R, int K, int OS, int KO) {
        int n = R * K;
        k_prep<<<(n + 255) / 256, 256, 0, stream>>>(src, dh, dl, R, K, OS, KO);
    };
    auto prep16 = [&](const float* src, _Float16* dst, int R, int K, int OS, int KO) {
        int n = R * K;
        k_prep16s<<<(n + 255) / 256, 256, 0, stream>>>(src, dst, R, K, OS, KO);
    };

    // LSTM1 combined [Wih | Whh] split-bf16, row stride 128
    prep(l1Wih0, w1h, w1l, 256, 32, 128, 0);
    prep(l1Whh0, w1h, w1l, 256, 64, 128, 32);
    for (int l = 1; l < 4; ++l) {
        prep(l1Wih + (l - 1) * 256 * 64, w1h + l * 256 * 128, w1l + l * 256 * 128, 256, 64, 128, 0);
        prep(l1Whh + (l - 1) * 256 * 64, w1h + l * 256 * 128, w1l + l * 256 * 128, 256, 64, 128, 64);
    }
    // LSTM2 combined fp16 [Wih (zero-padded to 128) | Whh], row stride 256
    hipMemsetAsync(wcomb, 0, (size_t)4 * 512 * 256 * 2, stream);
    prep16(l2Wih0, wcomb, 512, 64, 256, 0);
    prep16(l2Whh0, wcomb, 512, 128, 256, 128);
    for (int l = 1; l < 4; ++l) {
        prep16(l2Wih + (l - 1) * 512 * 128, wcomb + (size_t)l * 512 * 256, 512, 128, 256, 0);
        prep16(l2Whh + (l - 1) * 512 * 128, wcomb + (size_t)l * 512 * 256, 512, 128, 256, 128);
    }

    k_embed<<<(NTc * EMBc + 255) / 256, 256, 0, stream>>>(atoms, embw, seq1h, seq1l);

    for (int l = 0; l < 4; ++l) {
        const float* bp = (l == 0) ? l1b0 : l1b + (l - 1) * 256;
        if (l == 0)
            k_scan1<32><<<Ntot / 32, 256, 0, stream>>>(seq1h, seq1l, w1h, w1l, bp, dacc, 0, 1);
        else
            k_scan1<64><<<Ntot / 32, 256, 0, stream>>>(seq1h, seq1l,
                                                       w1h + l * 256 * 128, w1l + l * 256 * 128,
                                                       bp, dacc, 1, (l != 3) ? 1 : 0);
    }

    k_bn2_stats<<<32, 256, 0, stream>>>(lens, dacc, stats);
    k_bn2_apply<<<(R2c * 128 + 255) / 256, 256, 0, stream>>>(dacc, stats, lens, bn2g, bn2b, seqA);

    k_scan2c<<<8, 512, 0, stream>>>(seqA, wcomb, l2b0, l2b, hseq, c2);

    k_head<<<1, 256, 0, stream>>>(c2, bn3g, bn3b, w1, b1, w2, b2, w22, b22,
                                  w3, b3, w4, b4, w5, b5, out);

    (void)in_sizes; (void)n_in; (void)out_size; (void)ws_size;
}